// Round 11
// baseline (148.512 us; speedup 1.0000x reference)
//
#include <hip/hip_runtime.h>
#include <hip/hip_bf16.h>
#include <cstdint>
#include <cstddef>

typedef short short8 __attribute__((ext_vector_type(8)));
typedef float f32x4 __attribute__((ext_vector_type(4)));
typedef float f32x2 __attribute__((ext_vector_type(2)));

#define NS    2048
#define KPAD  288
#define H2    512
#define HID   256
#define WIN   2        // windows per segment (shared-core group)
#define SEGS  7        // segments per block
#define WPB   14       // windows per block = WIN*SEGS
#define SBLK  147      // ceil(2048/14)
#define SIGBLKS (8 * SBLK)   // 1176
#define CORE_STEPS (60 - WIN)   // 58
#define CORE_BACK  (59 - WIN)   // 57

#define MFMA(a,b,c) __builtin_amdgcn_mfma_f32_16x16x32_bf16((a),(b),(c),0,0,0)

__device__ __forceinline__ void gl2lds16(const void* g, void* l) {
    __builtin_amdgcn_global_load_lds(
        (const __attribute__((address_space(1))) void*)g,
        (__attribute__((address_space(3))) void*)l, 16, 0, 0);
}
__device__ __forceinline__ float geluf(float x) {
    return 0.5f * x * (1.0f + erff(x * 0.70710678118654752f));
}
__device__ __forceinline__ f32x4 shfl4(f32x4 v, int d) {
    f32x4 r;
    r[0] = __shfl_xor(v[0], d); r[1] = __shfl_xor(v[1], d);
    r[2] = __shfl_xor(v[2], d); r[3] = __shfl_xor(v[3], d);
    return r;
}
__device__ __forceinline__ f32x2 mk2(float a, float b) { f32x2 r; r[0] = a; r[1] = b; return r; }

struct Tbl3 { short col[729]; };
static constexpr Tbl3 make_tbl3() {
    Tbl3 t{};
    for (int x = 0; x < 729; ++x) t.col[x] = -1;
    int r = 0;
    for (int i = 0; i < 9; ++i)
        for (int j = 0; j < 9; ++j)
            for (int k = 0; k < 9; ++k) {
                bool lt1 = (i < j) || (i == j && (j < k || (j == k && k < i)));
                bool lt2 = (i < k) || (i == k && (j < i || (j == i && k < j)));
                if (lt1 && lt2) { t.col[(i*9+j)*9+k] = (short)(45 + r); ++r; }
            }
    return t;
}
static constexpr Tbl3 TBL3 = make_tbl3();

// ============================================================================
// sig: SHARED-CORE, WIN=2 (r10's WIN=4 template, refcheck-passed; parameter
// retuned on the measured model T ∝ work/resident_waves: r9 and r10 both hit
// ~46.5us at opposite ends (work 1.0/waves 12.5 vs work 0.4/waves 4.9);
// WIN=2 = work 0.52 at r9-level wave residency (1176 blocks, 4.6/CU).
// ============================================================================
#define SIG_STEPX(P,VA_,VB_,VC_) { \
    const float hh = 0.5f * S1i##P + vi * (1.0f/6.0f); \
    const float ra = S2ra##P + hh * (VA_); \
    const float rb = S2rb##P + hh * (VB_); \
    const float rc = S2rc##P + hh * (VC_); \
    const f32x2 ra2 = {ra, ra}, rb2 = {rb, rb}, rc2 = {rc, rc}; \
    S3sa##P += ra * v0; S3pa0##P += ra2*vp0; S3pa1##P += ra2*vp1; S3pa2##P += ra2*vp2; S3pa3##P += ra2*vp3; \
    S3sb##P += rb * v0; S3pb0##P += rb2*vp0; S3pb1##P += rb2*vp1; S3pb2##P += rb2*vp2; S3pb3##P += rb2*vp3; \
    S3sc##P += rc * v0; S3pc0##P += rc2*vp0; S3pc1##P += rc2*vp1; S3pc2##P += rc2*vp2; S3pc3##P += rc2*vp3; \
    const float aa = S1i##P + 0.5f * vi; \
    S2ra##P += aa * (VA_); S2rb##P += aa * (VB_); S2rc##P += aa * (VC_); \
    S1i##P += vi; }

#define DIFF_STEPR(PR,VA_,VB_,VC_) { \
    const float* pr_ = (PR); \
    const float4 e0 = *(const float4*)pr_; \
    const float4 e1 = *(const float4*)(pr_ + 4); \
    const float rs = pr_[ioff]; \
    const float v0 = DT; \
    const f32x2 vp0 = {e0.x, e0.y}, vp1 = {e0.z, e0.w}, vp2 = {e1.x, e1.y}, vp3 = {e1.z, e1.w}; \
    const float vi = (ci == 0) ? DT : rs; \
    SIG_STEPX(R,VA_,VB_,VC_) }

#define DIFF_STEPL(PR,VA_,VB_,VC_) { \
    const float* pr_ = (PR); \
    const float4 e0 = *(const float4*)pr_; \
    const float4 e1 = *(const float4*)(pr_ + 4); \
    const float rs = pr_[ioff]; \
    const float v0 = DT; \
    const f32x2 vp0 = {e0.x, e0.y}, vp1 = {e0.z, e0.w}, vp2 = {e1.x, e1.y}, vp3 = {e1.z, e1.w}; \
    const float vi = (ci == 0) ? DT : rs; \
    SIG_STEPX(,VA_,VB_,VC_) }

#define CORE(VA_,VB_,VC_) { \
    const float* pdc = &PD[(A0 - CORE_BACK) * 8]; \
    _Pragma("unroll 2") \
    for (int i_ = 0; i_ < CORE_STEPS; ++i_) { DIFF_STEPR(pdc, VA_,VB_,VC_) pdc += 8; } }

#define PHA(RA,RB,RC,VA_,VB_,VC_) { \
    if (j > 0) DIFF_STEPR(&PD[(A0 + j) * 8], VA_,VB_,VC_) \
    { const float* xr = &X[g0l * 8]; \
      const float4 e0 = *(const float4*)xr; \
      const float4 e1 = *(const float4*)(xr + 4); \
      const float rs = xr[ioff]; \
      const float v0 = 0.0f; \
      const f32x2 vp0 = {e0.x, e0.y}, vp1 = {e0.z, e0.w}, vp2 = {e1.x, e1.y}, vp3 = {e1.z, e1.w}; \
      const float vi = (ci == 0) ? 0.0f : rs; \
      SIG_STEPX(,VA_,VB_,VC_) } \
    { const float* pm = &PD[(A0 + j - 58) * 8]; \
      for (int i2 = 0; i2 < WIN - 1 - j; ++i2) { DIFF_STEPL(pm, VA_,VB_,VC_) pm += 8; } } \
    if (lt < 63) { \
        if ((RA) == 0) R1buf[seg * 9 + ci] = S1iR; \
        float* rb_ = &R2buf[seg * 81 + ci * 9]; \
        rb_[RA] = S2raR; rb_[RB] = S2rbR; rb_[RC] = S2rcR; } }

#define SIG_CMP(SL,M) { \
    const float* rr = &R2buf[seg * 81 + (M) * 9]; \
    const f32x2 l2q = {S2r##SL, S2r##SL}; \
    S3s##SL   += S1i * rr[0] + S2r##SL * r1_0 + S3s##SL##R; \
    S3p##SL##0 += s1i2 * mk2(rr[1], rr[2]) + l2q * r1q0 + S3p##SL##0R; \
    S3p##SL##1 += s1i2 * mk2(rr[3], rr[4]) + l2q * r1q1 + S3p##SL##1R; \
    S3p##SL##2 += s1i2 * mk2(rr[5], rr[6]) + l2q * r1q2 + S3p##SL##2R; \
    S3p##SL##3 += s1i2 * mk2(rr[7], rr[8]) + l2q * r1q3 + S3p##SL##3R; }

#define R1V(M) r1_##M

#define PHB(RA,RB,RC) { \
    const float* r1p = &R1buf[seg * 9]; \
    const float r1_0=r1p[0], r1_1=r1p[1], r1_2=r1p[2], r1_3=r1p[3], r1_4=r1p[4]; \
    const float r1_5=r1p[5], r1_6=r1p[6], r1_7=r1p[7], r1_8=r1p[8]; \
    const f32x2 s1i2 = {S1i, S1i}; \
    const f32x2 r1q0 = mk2(r1_1, r1_2), r1q1 = mk2(r1_3, r1_4); \
    const f32x2 r1q2 = mk2(r1_5, r1_6), r1q3 = mk2(r1_7, r1_8); \
    SIG_CMP(a,RA) SIG_CMP(b,RB) SIG_CMP(c,RC) \
    S2ra += S1i * R1V(RA) + S2raR; \
    S2rb += S1i * R1V(RB) + S2rbR; \
    S2rc += S1i * R1V(RC) + S2rcR; \
    S1i += S1iR; \
    if (lt < 63) { \
        if ((RA) == 0) W1buf[seg * 9 + ci] = S1i; \
        float* wb_ = &W2buf[seg * 81 + ci * 9]; \
        wb_[RA] = S2ra; wb_[RB] = S2rb; wb_[RC] = S2rc; } }

#define S3EL0(SL) S3s##SL
#define S3EL1(SL) S3p##SL##0[0]
#define S3EL2(SL) S3p##SL##0[1]
#define S3EL3(SL) S3p##SL##1[0]
#define S3EL4(SL) S3p##SL##1[1]
#define S3EL5(SL) S3p##SL##2[0]
#define S3EL6(SL) S3p##SL##2[1]
#define S3EL7(SL) S3p##SL##3[0]
#define S3EL8(SL) S3p##SL##3[1]

#define SIG_E2(SL,J2) if (ci < (J2)) { \
    const float val2 = S2r##SL - 0.5f * S1i * s1v##J2; \
    const int col2 = 9 + ci*8 - (ci*(ci-1))/2 + ((J2) - ci - 1); \
    frow[col2] = __float2bfloat16(val2); }

#define SIG_E3(SL,R,K) { const int col3 = TBL3.col[tb + (R)*9 + (K)]; \
    if (col3 >= 0) { \
        const float val3 = S3EL##K(SL) \
            - 0.5f * (S1i * S2w[(R)*9+(K)] + S2r##SL * s1v##K) \
            + S1i * s1v##R * s1v##K * (1.0f/3.0f); \
        frow[col3] = __float2bfloat16(val3); } }

#define SIG_E3R(SL,R) SIG_E3(SL,R,0) SIG_E3(SL,R,1) SIG_E3(SL,R,2) SIG_E3(SL,R,3) \
    SIG_E3(SL,R,4) SIG_E3(SL,R,5) SIG_E3(SL,R,6) SIG_E3(SL,R,7) SIG_E3(SL,R,8)

#define SIG_EMIT(RA,RB,RC) \
    if (act) { \
        if ((RA) == 0) { \
            frow[ci] = __float2bfloat16(S1i); \
            if (ci == 0) { \
                const __hip_bfloat16 z16 = __float2bfloat16(0.0f); \
                frow[285] = z16; frow[286] = z16; frow[287] = z16; \
            } \
        } \
        SIG_E2(a,RA) SIG_E2(b,RB) SIG_E2(c,RC) \
        SIG_E3R(a,RA) SIG_E3R(b,RB) SIG_E3R(c,RC) \
    }

#define PHC(RA,RB,RC) { \
    const float* s1p = &W1buf[seg * 9]; \
    const float s1v0=s1p[0], s1v1=s1p[1], s1v2=s1p[2], s1v3=s1p[3], s1v4=s1p[4]; \
    const float s1v5=s1p[5], s1v6=s1p[6], s1v7=s1p[7], s1v8=s1p[8]; \
    const float* S2w = &W2buf[seg * 81]; \
    const int tb = ci * 81; \
    __hip_bfloat16* frow = feats + (size_t)(b * NS + wj) * KPAD; \
    SIG_EMIT(RA,RB,RC) }

__global__ __launch_bounds__(192) __attribute__((amdgpu_waves_per_eu(1, 4)))
void sig_kernel(const float* __restrict__ x, __hip_bfloat16* __restrict__ feats,
                const float* __restrict__ w1, const float* __restrict__ w2,
                const float* __restrict__ lng, const float* __restrict__ lnb,
                const float* __restrict__ b2,
                __hip_bfloat16* __restrict__ w1T, __hip_bfloat16* __restrict__ w2g,
                float* __restrict__ gw, float* __restrict__ cvec) {
    __shared__ __align__(16) float X[73 * 8];
    __shared__ __align__(16) float PD[132 * 8];   // 59 zero-pad rows + up to 73 diff rows
    __shared__ float R1buf[SEGS * 9];
    __shared__ float R2buf[SEGS * 81];
    __shared__ float W1buf[SEGS * 9];
    __shared__ float W2buf[SEGS * 81];

    const int blk = blockIdx.x;
    const int tid = threadIdx.x;

    if (blk >= SIGBLKS) {
        // ---------------- prep tail blocks (r9, unchanged) ----------------
        const int pb = blk - SIGBLKS;
        if (pb < 256) {
            const int n = pb;
            float pa = 0.f, pc = 0.f;
            for (int k = tid; k < H2; k += 192) {
                const float wv = w2[(size_t)k * HID + n];
                const float a = lng[k] * wv;
                const float c = lnb[k] * wv;
                w2g[(size_t)n * H2 + k] = __float2bfloat16(a);
                pa += a; pc += c;
            }
#pragma unroll
            for (int d = 1; d < 64; d <<= 1) { pa += __shfl_xor(pa, d); pc += __shfl_xor(pc, d); }
            if ((tid & 63) == 0) { X[(tid >> 6) * 2] = pa; X[(tid >> 6) * 2 + 1] = pc; }
            __syncthreads();
            if (tid == 0) {
                gw[n]   = X[0] + X[2] + X[4];
                cvec[n] = X[1] + X[3] + X[5] + b2[n];
            }
        } else {
            const int n0 = (pb - 256) * 8;
            for (int e = tid; e < 8 * KPAD; e += 192) {
                const int ni = n0 + (e / KPAD);
                const int k  = e - (e / KPAD) * KPAD;
                const float v = (k < 285) ? w1[(size_t)k * H2 + ni] : 0.0f;
                w1T[(size_t)ni * KPAD + k] = __float2bfloat16(v);
            }
        }
        return;
    }

    // ---------------- sig blocks ----------------
    const int b   = blk / SBLK;
    const int s0  = (blk % SBLK) * WPB;
    const int lo  = (s0 - 59 > 0) ? (s0 - 59) : 0;
    const int hi  = (s0 + WPB - 1 < NS - 1) ? (s0 + WPB - 1) : (NS - 1);
    const int nrow = hi - lo + 1;     // <= 73

    {   // stage x rows
        const float4* src = (const float4*)(x + ((size_t)b * NS + lo) * 8);
        float4* X4 = (float4*)X;
        const int n4 = nrow * 2;
        for (int t = tid; t < n4; t += 192) X4[t] = src[t];
    }
    __syncthreads();
    {   // build padded diff rows (132 rows; zeros outside (0,nrow))
        const float4* X4 = (const float4*)X;
        float4* PD4 = (float4*)PD;
        for (int t = tid; t < 264; t += 192) {
            const int p = t >> 1;
            const int r = p - 59;
            float4 dv = {0.f, 0.f, 0.f, 0.f};
            if (r > 0 && r < nrow) {
                const float4 a = X4[t - 118], bb = X4[t - 120];
                dv.x = a.x - bb.x; dv.y = a.y - bb.y; dv.z = a.z - bb.z; dv.w = a.w - bb.w;
            }
            PD4[t] = dv;
        }
    }
    __syncthreads();

    const int t3    = tid >> 6;
    const int lt    = tid & 63;
    const int widx0 = lt / 9;
    const int ci    = lt - widx0 * 9;
    const int seg   = (widx0 < SEGS) ? widx0 : SEGS - 1;
    const int wbase = s0 + seg * WIN;
    const int A0    = 59 + (wbase - lo);     // padded row of d_{wbase}
    const int ioff  = (ci > 0) ? (ci - 1) : 0;
    const float DT  = 1.0f / 59.0f;

    // R-state (core chain)
    float S1iR = 0.f, S2raR = 0.f, S2rbR = 0.f, S2rcR = 0.f;
    float S3saR = 0.f, S3sbR = 0.f, S3scR = 0.f;
    f32x2 S3pa0R={0,0},S3pa1R={0,0},S3pa2R={0,0},S3pa3R={0,0};
    f32x2 S3pb0R={0,0},S3pb1R={0,0},S3pb2R={0,0},S3pb3R={0,0};
    f32x2 S3pc0R={0,0},S3pc1R={0,0},S3pc2R={0,0},S3pc3R={0,0};
    // L/W-state (mini chain, then composed window)
    float S1i, S2ra, S2rb, S2rc, S3sa, S3sb, S3sc;
    f32x2 S3pa0,S3pa1,S3pa2,S3pa3,S3pb0,S3pb1,S3pb2,S3pb3,S3pc0,S3pc1,S3pc2,S3pc3;

    // core: CORE_STEPS diff steps d_{wbase-CORE_BACK..wbase}
    if (t3 == 0)      { CORE(v0,   e0.x, e0.y) }
    else if (t3 == 1) { CORE(e0.z, e0.w, e1.x) }
    else              { CORE(e1.y, e1.z, e1.w) }

#pragma unroll 1
    for (int j = 0; j < WIN; ++j) {
        const int wj  = wbase + j;
        const bool act = (lt < 63) && (wj < NS);
        int g0 = wj - 59; if (g0 < 0) g0 = 0;
        const int g0l = g0 - lo;

        // zero L
        S1i = 0.f; S2ra = 0.f; S2rb = 0.f; S2rc = 0.f;
        S3sa = 0.f; S3sb = 0.f; S3sc = 0.f;
        S3pa0 = mk2(0,0); S3pa1 = mk2(0,0); S3pa2 = mk2(0,0); S3pa3 = mk2(0,0);
        S3pb0 = mk2(0,0); S3pb1 = mk2(0,0); S3pb2 = mk2(0,0); S3pb3 = mk2(0,0);
        S3pc0 = mk2(0,0); S3pc1 = mk2(0,0); S3pc2 = mk2(0,0); S3pc3 = mk2(0,0);

        if (t3 == 0)      { PHA(0,1,2, v0,   e0.x, e0.y) }
        else if (t3 == 1) { PHA(3,4,5, e0.z, e0.w, e1.x) }
        else              { PHA(6,7,8, e1.y, e1.z, e1.w) }
        __syncthreads();

        if (t3 == 0)      { PHB(0,1,2) }
        else if (t3 == 1) { PHB(3,4,5) }
        else              { PHB(6,7,8) }
        __syncthreads();

        if (t3 == 0)      { PHC(0,1,2) }
        else if (t3 == 1) { PHC(3,4,5) }
        else              { PHC(6,7,8) }
    }
}

// ============================================================================
// mlp_kernel: unchanged (control).
// ============================================================================
__global__ __launch_bounds__(256)
void mlp_kernel(const __hip_bfloat16* __restrict__ feats,
                const __hip_bfloat16* __restrict__ w1T,
                const float* __restrict__ bias,
                const __hip_bfloat16* __restrict__ w2g,
                const float* __restrict__ gw,
                const float* __restrict__ cvec,
                float* __restrict__ out) {
    __shared__ __align__(16) __hip_bfloat16 Blds[512 * 32];   // 32KB
    __shared__ __align__(16) __hip_bfloat16 Hbuf[32 * 512];   // 32KB
    __shared__ __align__(16) __hip_bfloat16 Ab0[32 * 32];
    __shared__ __align__(16) __hip_bfloat16 Ab1[32 * 32];
    __shared__ float sstat[4][32][2];

    const int tid  = threadIdx.x;
    const int wave = tid >> 6;
    const int lane = tid & 63;
    const int quad = lane >> 4;
    const int l16  = lane & 15;
    const int m0   = blockIdx.x * 32;
    const int swz16 = (quad ^ ((l16 >> 1) & 3)) * 16;

#define STAGE_B1(S, DST) { \
    _Pragma("unroll") \
    for (int i_ = 0; i_ < 8; ++i_) { \
        const int c_ = tid + i_ * 256; const int r_ = c_ >> 2; const int q_ = c_ & 3; \
        gl2lds16(w1T + (size_t)r_ * KPAD + (S) * 32 + ((q_ ^ ((r_ >> 1) & 3)) * 8), \
                 (char*)(DST) + (c_ & ~63) * 16); } }
#define STAGE_A(S, DST) { if (tid < 128) { \
        const int r_ = tid >> 2; const int q_ = tid & 3; \
        gl2lds16(feats + (size_t)(m0 + r_) * KPAD + (S) * 32 + ((q_ ^ ((r_ >> 1) & 3)) * 8), \
                 (char*)(DST) + (tid & ~63) * 16); } }
#define STAGE_B2(T, DST) { \
    _Pragma("unroll") \
    for (int i_ = 0; i_ < 4; ++i_) { \
        const int c_ = tid + i_ * 256; const int r_ = c_ >> 2; const int q_ = c_ & 3; \
        gl2lds16(w2g + (size_t)r_ * H2 + (T) * 32 + ((q_ ^ ((r_ >> 1) & 3)) * 8), \
                 (char*)(DST) + (c_ & ~63) * 16); } }

    ((float*)sstat)[tid] = 0.0f;
    STAGE_B1(0, Blds)
    STAGE_A(0, Ab0)
    __syncthreads();

    f32x4 a1[2][8];
#pragma unroll
    for (int mf = 0; mf < 2; ++mf)
#pragma unroll
        for (int nf = 0; nf < 8; ++nf) a1[mf][nf] = f32x4{0.f, 0.f, 0.f, 0.f};

#pragma unroll 1
    for (int s = 0; s < 9; ++s) {
        if (s < 8) {
            if ((s + 1) & 1) { STAGE_B1(s + 1, Hbuf) STAGE_A(s + 1, Ab1) }
            else             { STAGE_B1(s + 1, Blds) STAGE_A(s + 1, Ab0) }
        }
        const char* Ac = (s & 1) ? (const char*)Ab1 : (const char*)Ab0;
        const char* Bc = (s & 1) ? (const char*)Hbuf : (const char*)Blds;
        const short8 av0 = *(const short8*)(Ac + l16 * 64 + swz16);
        const short8 av1 = *(const short8*)(Ac + (16 + l16) * 64 + swz16);
#pragma unroll
        for (int nf = 0; nf < 8; ++nf) {
            const short8 bv = *(const short8*)(Bc + (size_t)(wave * 128 + nf * 16 + l16) * 64 + swz16);
            a1[0][nf] = MFMA(av0, bv, a1[0][nf]);
            a1[1][nf] = MFMA(av1, bv, a1[1][nf]);
        }
        __syncthreads();
    }

    {
        f32x4 sum0 = {0,0,0,0}, sum1 = {0,0,0,0}, sq0 = {0,0,0,0}, sq1 = {0,0,0,0};
#pragma unroll
        for (int nf = 0; nf < 8; ++nf) {
            const int col = wave * 128 + nf * 16 + l16;
            const float bv = bias[col];
            f32x4 e0, e1;
#pragma unroll
            for (int r = 0; r < 4; ++r) { e0[r] = geluf(a1[0][nf][r] + bv); e1[r] = geluf(a1[1][nf][r] + bv); }
#pragma unroll
            for (int r = 0; r < 4; ++r) {
                const int row0 = quad * 4 + r;
                const int row1 = 16 + row0;
                const int ch0 = (col >> 3) ^ (row0 & 7);
                const int ch1 = (col >> 3) ^ (row1 & 7);
                *(__hip_bfloat16*)((char*)Hbuf + row0 * 1024 + ch0 * 16 + (col & 7) * 2) = __float2bfloat16(e0[r]);
                *(__hip_bfloat16*)((char*)Hbuf + row1 * 1024 + ch1 * 16 + (col & 7) * 2) = __float2bfloat16(e1[r]);
            }
            sum0 += e0; sq0 += e0 * e0; sum1 += e1; sq1 += e1 * e1;
        }
        sum0 += shfl4(sum0, 1); sq0 += shfl4(sq0, 1); sum1 += shfl4(sum1, 1); sq1 += shfl4(sq1, 1);
        sum0 += shfl4(sum0, 2); sq0 += shfl4(sq0, 2); sum1 += shfl4(sum1, 2); sq1 += shfl4(sq1, 2);
        sum0 += shfl4(sum0, 4); sq0 += shfl4(sq0, 4); sum1 += shfl4(sum1, 4); sq1 += shfl4(sq1, 4);
        sum0 += shfl4(sum0, 8); sq0 += shfl4(sq0, 8); sum1 += shfl4(sum1, 8); sq1 += shfl4(sq1, 8);
        if (l16 == 0) {
#pragma unroll
            for (int r = 0; r < 4; ++r) {
                sstat[wave][quad * 4 + r][0]      = sum0[r];
                sstat[wave][quad * 4 + r][1]      = sq0[r];
                sstat[wave][16 + quad * 4 + r][0] = sum1[r];
                sstat[wave][16 + quad * 4 + r][1] = sq1[r];
            }
        }
        __syncthreads();
    }

    f32x4 a2[2][4];
#pragma unroll
    for (int mf = 0; mf < 2; ++mf)
#pragma unroll
        for (int nf = 0; nf < 4; ++nf) a2[mf][nf] = f32x4{0.f, 0.f, 0.f, 0.f};

    STAGE_B2(0, Blds)
    __syncthreads();

    const int hsw = l16 & 7;
#pragma unroll 1
    for (int t = 0; t < 16; ++t) {
        if (t < 15) { STAGE_B2(t + 1, (char*)Blds + ((t + 1) & 1) * 16384) }
        const char* Bc = (const char*)Blds + (t & 1) * 16384;
        const int kc = ((t * 4 + quad) ^ hsw) * 16;
        const short8 hv0 = *(const short8*)((const char*)Hbuf + l16 * 1024 + kc);
        const short8 hv1 = *(const short8*)((const char*)Hbuf + (16 + l16) * 1024 + kc);
#pragma unroll
        for (int nf = 0; nf < 4; ++nf) {
            const short8 bv = *(const short8*)(Bc + (size_t)(wave * 64 + nf * 16 + l16) * 64 + swz16);
            a2[0][nf] = MFMA(hv0, bv, a2[0][nf]);
            a2[1][nf] = MFMA(hv1, bv, a2[1][nf]);
        }
        __syncthreads();
    }

    f32x4 mu0, rs0, mu1, rs1;
#pragma unroll
    for (int r = 0; r < 4; ++r) {
        const int rl0 = quad * 4 + r, rl1 = 16 + rl0;
        const float s0 = sstat[0][rl0][0] + sstat[1][rl0][0] + sstat[2][rl0][0] + sstat[3][rl0][0];
        const float q0 = sstat[0][rl0][1] + sstat[1][rl0][1] + sstat[2][rl0][1] + sstat[3][rl0][1];
        const float s1 = sstat[0][rl1][0] + sstat[1][rl1][0] + sstat[2][rl1][0] + sstat[3][rl1][0];
        const float q1 = sstat[0][rl1][1] + sstat[1][rl1][1] + sstat[2][rl1][1] + sstat[3][rl1][1];
        mu0[r] = s0 * (1.0f / 512.0f);
        mu1[r] = s1 * (1.0f / 512.0f);
        rs0[r] = rsqrtf(q0 * (1.0f / 512.0f) - mu0[r] * mu0[r] + 1e-5f);
        rs1[r] = rsqrtf(q1 * (1.0f / 512.0f) - mu1[r] * mu1[r] + 1e-5f);
    }
#pragma unroll
    for (int nf = 0; nf < 4; ++nf) {
        const int col = wave * 64 + nf * 16 + l16;
        const float g_ = gw[col], c_ = cvec[col];
#pragma unroll
        for (int r = 0; r < 4; ++r) {
            const int row0 = m0 + quad * 4 + r;
            const int row1 = row0 + 16;
            out[(size_t)row0 * HID + col] = rs0[r] * (a2[0][nf][r] - mu0[r] * g_) + c_;
            out[(size_t)row1 * HID + col] = rs1[r] * (a2[1][nf][r] - mu1[r] * g_) + c_;
        }
    }
}

// ============================================================================
extern "C" void kernel_launch(void* const* d_in, const int* in_sizes, int n_in,
                              void* d_out, int out_size, void* d_ws, size_t ws_size,
                              hipStream_t stream) {
    const float* x   = (const float*)d_in[0];
    const float* w1  = (const float*)d_in[1];
    const float* b1  = (const float*)d_in[2];
    const float* lng = (const float*)d_in[3];
    const float* lnb = (const float*)d_in[4];
    const float* w2  = (const float*)d_in[5];
    const float* b2  = (const float*)d_in[6];
    float* out = (float*)d_out;

    char* ws = (char*)d_ws;
    __hip_bfloat16* feats = (__hip_bfloat16*)(ws);                        // 9437184
    __hip_bfloat16* w1T   = (__hip_bfloat16*)(ws + 9437184);              // 294912 (512x288)
    __hip_bfloat16* w2g   = (__hip_bfloat16*)(ws + 9732096);              // 262144 (256x512)
    float*          gw    = (float*)(ws + 9994240);                       // 1024
    float*          cvec  = (float*)(ws + 9995264);                       // 1024

    sig_kernel<<<dim3(SIGBLKS + 320), dim3(192), 0, stream>>>(
        x, feats, w1, w2, lng, lnb, b2, w1T, w2g, gw, cvec);
    mlp_kernel<<<dim3(512), dim3(256), 0, stream>>>(feats, w1T, b1, w2g, gw, cvec, out);
}

// Round 12
// 146.629 us; speedup vs baseline: 1.0128x; 1.0128x over previous
//
#include <hip/hip_runtime.h>
#include <hip/hip_bf16.h>
#include <cstdint>
#include <cstddef>

typedef short short8 __attribute__((ext_vector_type(8)));
typedef float f32x4 __attribute__((ext_vector_type(4)));
typedef float f32x2 __attribute__((ext_vector_type(2)));

#define NS    2048
#define KPAD  288
#define H2    512
#define HID   256
#define WPB   7       // windows per sig workgroup (192 thr = 3 waves = 3 thirds)
#define SBLK  293     // ceil(2048/7)
#define SIGBLKS (8 * SBLK)   // 2344

#define MFMA(a,b,c) __builtin_amdgcn_mfma_f32_16x16x32_bf16((a),(b),(c),0,0,0)

__device__ __forceinline__ void gl2lds16(const void* g, void* l) {
    __builtin_amdgcn_global_load_lds(
        (const __attribute__((address_space(1))) void*)g,
        (__attribute__((address_space(3))) void*)l, 16, 0, 0);
}
__device__ __forceinline__ float geluf(float x) {
    return 0.5f * x * (1.0f + erff(x * 0.70710678118654752f));
}
__device__ __forceinline__ f32x4 shfl4(f32x4 v, int d) {
    f32x4 r;
    r[0] = __shfl_xor(v[0], d); r[1] = __shfl_xor(v[1], d);
    r[2] = __shfl_xor(v[2], d); r[3] = __shfl_xor(v[3], d);
    return r;
}

struct Tbl3 { short col[729]; };
static constexpr Tbl3 make_tbl3() {
    Tbl3 t{};
    for (int x = 0; x < 729; ++x) t.col[x] = -1;
    int r = 0;
    for (int i = 0; i < 9; ++i)
        for (int j = 0; j < 9; ++j)
            for (int k = 0; k < 9; ++k) {
                bool lt1 = (i < j) || (i == j && (j < k || (j == k && k < i)));
                bool lt2 = (i < k) || (i == k && (j < i || (j == i && k < j)));
                if (lt1 && lt2) { t.col[(i*9+j)*9+k] = (short)(45 + r); ++r; }
            }
    return t;
}
static constexpr Tbl3 TBL3 = make_tbl3();

// ============================================================================
// sig: r9 version verbatim — measured session best (146.6us total, sig 46.9).
// r6 body (prefetch-2, waves_per_eu(1,6)) + prep folded as 320 tail blocks.
// Structural note for posterity: sig is latency-bound at ~4.5%/wave issue;
// T = work/VALUBusy and VALUBusy tracks total grid work, so work-reduction
// rewrites (shared-core r10/r11, refcheck-passed) do NOT reduce time.
// ============================================================================
#define SIG_STEP(VA_,VB_,VC_) { \
    const float hh = 0.5f * S1i + vi * (1.0f/6.0f); \
    const float ra = S2ra + hh * (VA_); \
    const float rb = S2rb + hh * (VB_); \
    const float rc = S2rc + hh * (VC_); \
    const f32x2 ra2 = {ra, ra}, rb2 = {rb, rb}, rc2 = {rc, rc}; \
    S3sa += ra * v0; S3pa0 += ra2*vp0; S3pa1 += ra2*vp1; S3pa2 += ra2*vp2; S3pa3 += ra2*vp3; \
    S3sb += rb * v0; S3pb0 += rb2*vp0; S3pb1 += rb2*vp1; S3pb2 += rb2*vp2; S3pb3 += rb2*vp3; \
    S3sc += rc * v0; S3pc0 += rc2*vp0; S3pc1 += rc2*vp1; S3pc2 += rc2*vp2; S3pc3 += rc2*vp3; \
    const float aa = S1i + 0.5f * vi; \
    S2ra += aa * (VA_); S2rb += aa * (VB_); S2rc += aa * (VC_); \
    S1i += vi; }

#define SIG_DSTEP(E0,E1,RS,VA_,VB_,VC_) { \
    const float4 e0 = (E0); const float4 e1 = (E1); const float rs = (RS); \
    const float v0 = DT; \
    const f32x2 vp0 = {e0.x, e0.y}, vp1 = {e0.z, e0.w}, vp2 = {e1.x, e1.y}, vp3 = {e1.z, e1.w}; \
    const float vi = (ci == 0) ? DT : rs; \
    SIG_STEP(VA_,VB_,VC_) }

#define SIG_MAIN(VA_,VB_,VC_) { \
    { const float* xr = &X[(g0 - lo) * 8]; \
      const float4 e0 = *(const float4*)xr; \
      const float4 e1 = *(const float4*)(xr + 4); \
      const float rs = xr[ioff]; \
      const float v0 = 0.0f; \
      const f32x2 vp0 = {e0.x, e0.y}, vp1 = {e0.z, e0.w}, vp2 = {e1.x, e1.y}, vp3 = {e1.z, e1.w}; \
      const float vi = (ci == 0) ? 0.0f : rs; \
      SIG_STEP(VA_,VB_,VC_) } \
    const float* pd = &PD[(sm59 + 1 - lo + 59) * 8]; \
    float4 p0 = *(const float4*)pd; \
    float4 p1 = *(const float4*)(pd + 4); \
    float  pr = pd[ioff]; \
    float4 q0 = *(const float4*)(pd + 8); \
    float4 q1 = *(const float4*)(pd + 12); \
    float  qr = (pd + 8)[ioff]; \
    _Pragma("unroll 1") \
    for (int j = 1; j < 59; j += 2) { \
      pd += 16; \
      const float4 a0 = *(const float4*)pd; \
      const float4 a1 = *(const float4*)(pd + 4); \
      const float  ar = pd[ioff]; \
      const float4 b0 = *(const float4*)(pd + 8); \
      const float4 b1 = *(const float4*)(pd + 12); \
      const float  br = (pd + 8)[ioff]; \
      SIG_DSTEP(p0, p1, pr, VA_,VB_,VC_) \
      SIG_DSTEP(q0, q1, qr, VA_,VB_,VC_) \
      p0 = a0; p1 = a1; pr = ar; \
      q0 = b0; q1 = b1; qr = br; \
    } \
    SIG_DSTEP(p0, p1, pr, VA_,VB_,VC_) }

#define SIG_ST(RA,RB,RC) \
    if (act) { \
        if ((RA) == 0) S1buf[widx * 9 + ci] = S1i; \
        float* sb = &S2buf[widx * 81 + ci * 9]; \
        sb[RA] = S2ra; sb[RB] = S2rb; sb[RC] = S2rc; \
    }

#define S3EL0(SL) S3s##SL
#define S3EL1(SL) S3p##SL##0[0]
#define S3EL2(SL) S3p##SL##0[1]
#define S3EL3(SL) S3p##SL##1[0]
#define S3EL4(SL) S3p##SL##1[1]
#define S3EL5(SL) S3p##SL##2[0]
#define S3EL6(SL) S3p##SL##2[1]
#define S3EL7(SL) S3p##SL##3[0]
#define S3EL8(SL) S3p##SL##3[1]

#define SIG_E2(SL,J2) if (ci < (J2)) { \
    const float val2 = S2r##SL - 0.5f * S1i * s1v##J2; \
    const int col2 = 9 + ci*8 - (ci*(ci-1))/2 + ((J2) - ci - 1); \
    frow[col2] = __float2bfloat16(val2); }

#define SIG_E3(SL,R,K) { const int col3 = TBL3.col[tb + (R)*9 + (K)]; \
    if (col3 >= 0) { \
        const float val3 = S3EL##K(SL) \
            - 0.5f * (S1i * S2w[(R)*9+(K)] + S2r##SL * s1v##K) \
            + S1i * s1v##R * s1v##K * (1.0f/3.0f); \
        frow[col3] = __float2bfloat16(val3); } }

#define SIG_E3R(SL,R) SIG_E3(SL,R,0) SIG_E3(SL,R,1) SIG_E3(SL,R,2) SIG_E3(SL,R,3) \
    SIG_E3(SL,R,4) SIG_E3(SL,R,5) SIG_E3(SL,R,6) SIG_E3(SL,R,7) SIG_E3(SL,R,8)

#define SIG_EMIT(RA,RB,RC) \
    if (act) { \
        if ((RA) == 0) { \
            frow[ci] = __float2bfloat16(S1i); \
            if (ci == 0) { \
                const __hip_bfloat16 z16 = __float2bfloat16(0.0f); \
                frow[285] = z16; frow[286] = z16; frow[287] = z16; \
            } \
        } \
        SIG_E2(a,RA) SIG_E2(b,RB) SIG_E2(c,RC) \
        SIG_E3R(a,RA) SIG_E3R(b,RB) SIG_E3R(c,RC) \
    }

__global__ __launch_bounds__(192) __attribute__((amdgpu_waves_per_eu(1, 6)))
void sig_kernel(const float* __restrict__ x, __hip_bfloat16* __restrict__ feats,
                const float* __restrict__ w1, const float* __restrict__ w2,
                const float* __restrict__ lng, const float* __restrict__ lnb,
                const float* __restrict__ b2,
                __hip_bfloat16* __restrict__ w1T, __hip_bfloat16* __restrict__ w2g,
                float* __restrict__ gw, float* __restrict__ cvec) {
    __shared__ __align__(16) float X[66 * 8];
    __shared__ __align__(16) float PD[126 * 8];   // rows 0..58 zero pad, 59+r = x[lo+r]-x[lo+r-1]
    __shared__ float S2buf[WPB * 81];
    __shared__ float S1buf[WPB * 9];

    const int blk = blockIdx.x;
    const int tid = threadIdx.x;

    if (blk >= SIGBLKS) {
        // ---------------- prep tail blocks ----------------
        const int pb = blk - SIGBLKS;
        if (pb < 256) {
            // w2g column n: w2g[n][k] = g_k*w2[k][n]; gw[n] = sum a; cvec[n] = sum c + b2[n]
            const int n = pb;
            float pa = 0.f, pc = 0.f;
            for (int k = tid; k < H2; k += 192) {
                const float wv = w2[(size_t)k * HID + n];
                const float a = lng[k] * wv;
                const float c = lnb[k] * wv;
                w2g[(size_t)n * H2 + k] = __float2bfloat16(a);
                pa += a; pc += c;
            }
#pragma unroll
            for (int d = 1; d < 64; d <<= 1) { pa += __shfl_xor(pa, d); pc += __shfl_xor(pc, d); }
            if ((tid & 63) == 0) { X[(tid >> 6) * 2] = pa; X[(tid >> 6) * 2 + 1] = pc; }
            __syncthreads();
            if (tid == 0) {
                gw[n]   = X[0] + X[2] + X[4];
                cvec[n] = X[1] + X[3] + X[5] + b2[n];
            }
        } else {
            // w1T rows: 64 blocks x 8 n-rows each
            const int n0 = (pb - 256) * 8;
            for (int e = tid; e < 8 * KPAD; e += 192) {
                const int ni = n0 + (e / KPAD);
                const int k  = e - (e / KPAD) * KPAD;
                const float v = (k < 285) ? w1[(size_t)k * H2 + ni] : 0.0f;
                w1T[(size_t)ni * KPAD + k] = __float2bfloat16(v);
            }
        }
        return;
    }

    // ---------------- sig blocks (r6 body verbatim) ----------------
    const int b   = blk / SBLK;
    const int s0  = (blk % SBLK) * WPB;
    const int lo  = (s0 - 59 > 0) ? (s0 - 59) : 0;
    const int hi  = (s0 + WPB - 1 < NS - 1) ? (s0 + WPB - 1) : (NS - 1);
    const int nrow = hi - lo + 1;     // <= 66

    {   // stage x rows
        const float4* src = (const float4*)(x + ((size_t)b * NS + lo) * 8);
        float4* X4 = (float4*)X;
        const int n4 = nrow * 2;
        for (int t = tid; t < n4; t += 192) X4[t] = src[t];
    }
    __syncthreads();
    {   // build padded diff rows
        const float4* X4 = (const float4*)X;
        float4* PD4 = (float4*)PD;
        for (int t = tid; t < 252; t += 192) {
            const int p = t >> 1;         // padded row
            const int r = p - 59;         // diff row
            float4 dv = {0.f, 0.f, 0.f, 0.f};
            if (r > 0 && r < nrow) {
                const float4 a = X4[t - 118], bb = X4[t - 120];
                dv.x = a.x - bb.x; dv.y = a.y - bb.y; dv.z = a.z - bb.z; dv.w = a.w - bb.w;
            }
            PD4[t] = dv;
        }
    }
    __syncthreads();

    const int t3    = tid >> 6;           // third (wave-uniform): rows {0,1,2}/{3,4,5}/{6,7,8}
    const int lt    = tid & 63;
    const int widx0 = lt / 9;             // 0..7 (lane 63 idle)
    const int ci    = lt - widx0 * 9;     // slab index 0..8
    const bool act  = (lt < 63) && (s0 + widx0 < NS);
    const int widx  = (widx0 < WPB - 1) ? widx0 : WPB - 1;
    int s = s0 + widx; if (s > NS - 1) s = NS - 1;

    float S3sa=0.f, S3sb=0.f, S3sc=0.f;
    f32x2 S3pa0={0.f,0.f},S3pa1={0.f,0.f},S3pa2={0.f,0.f},S3pa3={0.f,0.f};
    f32x2 S3pb0={0.f,0.f},S3pb1={0.f,0.f},S3pb2={0.f,0.f},S3pb3={0.f,0.f};
    f32x2 S3pc0={0.f,0.f},S3pc1={0.f,0.f},S3pc2={0.f,0.f},S3pc3={0.f,0.f};
    float S2ra=0.f, S2rb=0.f, S2rc=0.f;
    float S1i = 0.f;
    const int ioff = (ci > 0) ? (ci - 1) : 0;
    const int sm59 = s - 59;
    const int g0   = (sm59 > 0) ? sm59 : 0;
    const float DT = 1.0f / 59.0f;

    if (t3 == 0)      { SIG_MAIN(v0,   e0.x, e0.y) }
    else if (t3 == 1) { SIG_MAIN(e0.z, e0.w, e1.x) }
    else              { SIG_MAIN(e1.y, e1.z, e1.w) }

    if (t3 == 0)      { SIG_ST(0,1,2) }
    else if (t3 == 1) { SIG_ST(3,4,5) }
    else              { SIG_ST(6,7,8) }
    __syncthreads();

    const float* s1p = &S1buf[widx * 9];
    const float s1v0=s1p[0], s1v1=s1p[1], s1v2=s1p[2], s1v3=s1p[3], s1v4=s1p[4];
    const float s1v5=s1p[5], s1v6=s1p[6], s1v7=s1p[7], s1v8=s1p[8];
    const float* S2w = &S2buf[widx * 81];
    const int tb = ci * 81;
    __hip_bfloat16* frow = feats + (size_t)(b * NS + s) * KPAD;

    if (t3 == 0)      { SIG_EMIT(0,1,2) }
    else if (t3 == 1) { SIG_EMIT(3,4,5) }
    else              { SIG_EMIT(6,7,8) }
}

// ============================================================================
// mlp_kernel: fused gemm1 + GELU + LN-stats + gemm2 + LN-epilogue (unchanged,
// control — r9 measured pass at 146.6 total).
// ============================================================================
__global__ __launch_bounds__(256)
void mlp_kernel(const __hip_bfloat16* __restrict__ feats,
                const __hip_bfloat16* __restrict__ w1T,
                const float* __restrict__ bias,
                const __hip_bfloat16* __restrict__ w2g,
                const float* __restrict__ gw,
                const float* __restrict__ cvec,
                float* __restrict__ out) {
    __shared__ __align__(16) __hip_bfloat16 Blds[512 * 32];   // 32KB
    __shared__ __align__(16) __hip_bfloat16 Hbuf[32 * 512];   // 32KB (B-dbuf partner, then h)
    __shared__ __align__(16) __hip_bfloat16 Ab0[32 * 32];     // 2KB
    __shared__ __align__(16) __hip_bfloat16 Ab1[32 * 32];     // 2KB
    __shared__ float sstat[4][32][2];                          // 1KB

    const int tid  = threadIdx.x;
    const int wave = tid >> 6;
    const int lane = tid & 63;
    const int quad = lane >> 4;
    const int l16  = lane & 15;
    const int m0   = blockIdx.x * 32;
    const int swz16 = (quad ^ ((l16 >> 1) & 3)) * 16;   // read swizzle, all [R][32k] tiles

#define STAGE_B1(S, DST) { \
    _Pragma("unroll") \
    for (int i_ = 0; i_ < 8; ++i_) { \
        const int c_ = tid + i_ * 256; const int r_ = c_ >> 2; const int q_ = c_ & 3; \
        gl2lds16(w1T + (size_t)r_ * KPAD + (S) * 32 + ((q_ ^ ((r_ >> 1) & 3)) * 8), \
                 (char*)(DST) + (c_ & ~63) * 16); } }
#define STAGE_A(S, DST) { if (tid < 128) { \
        const int r_ = tid >> 2; const int q_ = tid & 3; \
        gl2lds16(feats + (size_t)(m0 + r_) * KPAD + (S) * 32 + ((q_ ^ ((r_ >> 1) & 3)) * 8), \
                 (char*)(DST) + (tid & ~63) * 16); } }
#define STAGE_B2(T, DST) { \
    _Pragma("unroll") \
    for (int i_ = 0; i_ < 4; ++i_) { \
        const int c_ = tid + i_ * 256; const int r_ = c_ >> 2; const int q_ = c_ & 3; \
        gl2lds16(w2g + (size_t)r_ * H2 + (T) * 32 + ((q_ ^ ((r_ >> 1) & 3)) * 8), \
                 (char*)(DST) + (c_ & ~63) * 16); } }

    // zero stats + prologue stage
    ((float*)sstat)[tid] = 0.0f;
    STAGE_B1(0, Blds)
    STAGE_A(0, Ab0)
    __syncthreads();

    // ---------------- GEMM1: 32x512, K=288 ----------------
    f32x4 a1[2][8];
#pragma unroll
    for (int mf = 0; mf < 2; ++mf)
#pragma unroll
        for (int nf = 0; nf < 8; ++nf) a1[mf][nf] = f32x4{0.f, 0.f, 0.f, 0.f};

#pragma unroll 1
    for (int s = 0; s < 9; ++s) {
        if (s < 8) {
            if ((s + 1) & 1) { STAGE_B1(s + 1, Hbuf) STAGE_A(s + 1, Ab1) }
            else             { STAGE_B1(s + 1, Blds) STAGE_A(s + 1, Ab0) }
        }
        const char* Ac = (s & 1) ? (const char*)Ab1 : (const char*)Ab0;
        const char* Bc = (s & 1) ? (const char*)Hbuf : (const char*)Blds;
        const short8 av0 = *(const short8*)(Ac + l16 * 64 + swz16);
        const short8 av1 = *(const short8*)(Ac + (16 + l16) * 64 + swz16);
#pragma unroll
        for (int nf = 0; nf < 8; ++nf) {
            const short8 bv = *(const short8*)(Bc + (size_t)(wave * 128 + nf * 16 + l16) * 64 + swz16);
            a1[0][nf] = MFMA(av0, bv, a1[0][nf]);
            a1[1][nf] = MFMA(av1, bv, a1[1][nf]);
        }
        __syncthreads();
    }

    // ---------------- GELU epilogue -> Hbuf (swizzled) + stats ----------------
    {
        f32x4 sum0 = {0,0,0,0}, sum1 = {0,0,0,0}, sq0 = {0,0,0,0}, sq1 = {0,0,0,0};
#pragma unroll
        for (int nf = 0; nf < 8; ++nf) {
            const int col = wave * 128 + nf * 16 + l16;
            const float bv = bias[col];
            f32x4 e0, e1;
#pragma unroll
            for (int r = 0; r < 4; ++r) { e0[r] = geluf(a1[0][nf][r] + bv); e1[r] = geluf(a1[1][nf][r] + bv); }
#pragma unroll
            for (int r = 0; r < 4; ++r) {
                const int row0 = quad * 4 + r;
                const int row1 = 16 + row0;
                const int ch0 = (col >> 3) ^ (row0 & 7);
                const int ch1 = (col >> 3) ^ (row1 & 7);
                *(__hip_bfloat16*)((char*)Hbuf + row0 * 1024 + ch0 * 16 + (col & 7) * 2) = __float2bfloat16(e0[r]);
                *(__hip_bfloat16*)((char*)Hbuf + row1 * 1024 + ch1 * 16 + (col & 7) * 2) = __float2bfloat16(e1[r]);
            }
            sum0 += e0; sq0 += e0 * e0; sum1 += e1; sq1 += e1 * e1;
        }
        sum0 += shfl4(sum0, 1); sq0 += shfl4(sq0, 1); sum1 += shfl4(sum1, 1); sq1 += shfl4(sq1, 1);
        sum0 += shfl4(sum0, 2); sq0 += shfl4(sq0, 2); sum1 += shfl4(sum1, 2); sq1 += shfl4(sq1, 2);
        sum0 += shfl4(sum0, 4); sq0 += shfl4(sq0, 4); sum1 += shfl4(sum1, 4); sq1 += shfl4(sq1, 4);
        sum0 += shfl4(sum0, 8); sq0 += shfl4(sq0, 8); sum1 += shfl4(sum1, 8); sq1 += shfl4(sq1, 8);
        if (l16 == 0) {
#pragma unroll
            for (int r = 0; r < 4; ++r) {
                sstat[wave][quad * 4 + r][0]      = sum0[r];
                sstat[wave][quad * 4 + r][1]      = sq0[r];
                sstat[wave][16 + quad * 4 + r][0] = sum1[r];
                sstat[wave][16 + quad * 4 + r][1] = sq1[r];
            }
        }
        __syncthreads();
    }

    // ---------------- GEMM2: 32x256, K=512, A from Hbuf ----------------
    f32x4 a2[2][4];
#pragma unroll
    for (int mf = 0; mf < 2; ++mf)
#pragma unroll
        for (int nf = 0; nf < 4; ++nf) a2[mf][nf] = f32x4{0.f, 0.f, 0.f, 0.f};

    STAGE_B2(0, Blds)
    __syncthreads();

    const int hsw = l16 & 7;
#pragma unroll 1
    for (int t = 0; t < 16; ++t) {
        if (t < 15) { STAGE_B2(t + 1, (char*)Blds + ((t + 1) & 1) * 16384) }
        const char* Bc = (const char*)Blds + (t & 1) * 16384;
        const int kc = ((t * 4 + quad) ^ hsw) * 16;
        const short8 hv0 = *(const short8*)((const char*)Hbuf + l16 * 1024 + kc);
        const short8 hv1 = *(const short8*)((const char*)Hbuf + (16 + l16) * 1024 + kc);
#pragma unroll
        for (int nf = 0; nf < 4; ++nf) {
            const short8 bv = *(const short8*)(Bc + (size_t)(wave * 64 + nf * 16 + l16) * 64 + swz16);
            a2[0][nf] = MFMA(hv0, bv, a2[0][nf]);
            a2[1][nf] = MFMA(hv1, bv, a2[1][nf]);
        }
        __syncthreads();
    }

    // ---------------- LN epilogue + out ----------------
    f32x4 mu0, rs0, mu1, rs1;
#pragma unroll
    for (int r = 0; r < 4; ++r) {
        const int rl0 = quad * 4 + r, rl1 = 16 + rl0;
        const float s0 = sstat[0][rl0][0] + sstat[1][rl0][0] + sstat[2][rl0][0] + sstat[3][rl0][0];
        const float q0 = sstat[0][rl0][1] + sstat[1][rl0][1] + sstat[2][rl0][1] + sstat[3][rl0][1];
        const float s1 = sstat[0][rl1][0] + sstat[1][rl1][0] + sstat[2][rl1][0] + sstat[3][rl1][0];
        const float q1 = sstat[0][rl1][1] + sstat[1][rl1][1] + sstat[2][rl1][1] + sstat[3][rl1][1];
        mu0[r] = s0 * (1.0f / 512.0f);
        mu1[r] = s1 * (1.0f / 512.0f);
        rs0[r] = rsqrtf(q0 * (1.0f / 512.0f) - mu0[r] * mu0[r] + 1e-5f);
        rs1[r] = rsqrtf(q1 * (1.0f / 512.0f) - mu1[r] * mu1[r] + 1e-5f);
    }
#pragma unroll
    for (int nf = 0; nf < 4; ++nf) {
        const int col = wave * 64 + nf * 16 + l16;
        const float g_ = gw[col], c_ = cvec[col];
#pragma unroll
        for (int r = 0; r < 4; ++r) {
            const int row0 = m0 + quad * 4 + r;
            const int row1 = row0 + 16;
            out[(size_t)row0 * HID + col] = rs0[r] * (a2[0][nf][r] - mu0[r] * g_) + c_;
            out[(size_t)row1 * HID + col] = rs1[r] * (a2[1][nf][r] - mu1[r] * g_) + c_;
        }
    }
}

// ============================================================================
extern "C" void kernel_launch(void* const* d_in, const int* in_sizes, int n_in,
                              void* d_out, int out_size, void* d_ws, size_t ws_size,
                              hipStream_t stream) {
    const float* x   = (const float*)d_in[0];
    const float* w1  = (const float*)d_in[1];
    const float* b1  = (const float*)d_in[2];
    const float* lng = (const float*)d_in[3];
    const float* lnb = (const float*)d_in[4];
    const float* w2  = (const float*)d_in[5];
    const float* b2  = (const float*)d_in[6];
    float* out = (float*)d_out;

    char* ws = (char*)d_ws;
    __hip_bfloat16* feats = (__hip_bfloat16*)(ws);                        // 9437184
    __hip_bfloat16* w1T   = (__hip_bfloat16*)(ws + 9437184);              // 294912 (512x288)
    __hip_bfloat16* w2g   = (__hip_bfloat16*)(ws + 9732096);              // 262144 (256x512)
    float*          gw    = (float*)(ws + 9994240);                       // 1024
    float*          cvec  = (float*)(ws + 9995264);                       // 1024

    sig_kernel<<<dim3(SIGBLKS + 320), dim3(192), 0, stream>>>(
        x, feats, w1, w2, lng, lnb, b2, w1T, w2g, gw, cvec);
    mlp_kernel<<<dim3(512), dim3(256), 0, stream>>>(feats, w1T, b1, w2g, gw, cvec, out);
}